// Round 3
// baseline (1098.522 us; speedup 1.0000x reference)
//
#include <hip/hip_runtime.h>

#ifndef B_GRAPHS
#define B_GRAPHS 512
#endif

#define RPG 8  // rows per 32-lane group

typedef float f32x4 __attribute__((ext_vector_type(4)));

// Fused unbatch+pad, gather-formulated, single kernel.
// grid.y = graph b. Per wave: lanes 0,1 binary-search lower_bound(bv, b)
// and lower_bound(bv, b+1) (bv sorted => cumsum-of-bincount == first
// occurrence), broadcast via shfl. bv is 2 MB -> L2-resident, searches
// hide under other waves' streaming.
// Each 32-lane group moves RPG consecutive rows; lane moves one float4/row
// (D=128 = 32 x float4). Nontemporal: read-once / write-once streams.
__global__ void gather_pad_fused(const f32x4* __restrict__ vals4,
                                 const int* __restrict__ y,
                                 const int* __restrict__ bv, int n,
                                 f32x4* __restrict__ enc4,
                                 float* __restrict__ tgt,
                                 float* __restrict__ msk,
                                 int max_len) {
    const int b = blockIdx.y;

    // --- per-wave offsets: lanes 0,1 search keys b, b+1 ---
    const int lane64 = threadIdx.x & 63;
    int lo = 0;
    if (lane64 < 2) {
        int key = b + lane64;
        int hi = n;
        while (lo < hi) {
            int mid = (lo + hi) >> 1;
            if (bv[mid] < key) lo = mid + 1; else hi = mid;
        }
    }
    const int start = __shfl(lo, 0, 64);
    const int size  = __shfl(lo, 1, 64) - start;

    // --- streaming gather ---
    const int group = threadIdx.x >> 5;            // 8 groups / 256-thr block
    const int lane  = threadIdx.x & 31;
    const int pos0  = (blockIdx.x * (blockDim.x >> 5) + group) * RPG;

    f32x4 v[RPG];
    #pragma unroll
    for (int r = 0; r < RPG; ++r) {
        int pos = pos0 + r;
        f32x4 z = {0.f, 0.f, 0.f, 0.f};
        v[r] = z;
        if (pos < size)
            v[r] = __builtin_nontemporal_load(&vals4[(size_t)(start + pos) * 32 + lane]);
    }

    const size_t rowbase = (size_t)b * max_len + pos0;
    #pragma unroll
    for (int r = 0; r < RPG; ++r) {
        int pos = pos0 + r;
        if (pos < max_len)
            __builtin_nontemporal_store(v[r], &enc4[(rowbase + r) * 32 + lane]);
    }

    // targets + mask: lanes 0..RPG-1 write RPG contiguous floats (coalesced).
    if (lane < RPG) {
        int pos = pos0 + lane;
        if (pos < max_len) {
            bool valid = pos < size;
            float t = valid ? (float)y[start + pos] : 0.0f;
            __builtin_nontemporal_store(t, &tgt[rowbase + lane]);
            __builtin_nontemporal_store(valid ? 1.0f : 0.0f, &msk[rowbase + lane]);
        }
    }
}

extern "C" void kernel_launch(void* const* d_in, const int* in_sizes, int n_in,
                              void* d_out, int out_size, void* d_ws, size_t ws_size,
                              hipStream_t stream) {
    const float* values = (const float*)d_in[0];
    const int*   y      = (const int*)d_in[1];
    const int*   bv     = (const int*)d_in[2];

    const int N = in_sizes[1];            // 500000 nodes
    const int D = in_sizes[0] / N;        // 128
    const int B = B_GRAPHS;               // 512 (compile-time in reference)
    const int max_len = out_size / (B * (D + 2));
    const int total_rows = B * max_len;

    f32x4* enc4 = (f32x4*)d_out;
    float* tgt  = (float*)d_out + (size_t)total_rows * D;
    float* msk  = (float*)d_out + (size_t)total_rows * (D + 1);

    int threads = 256;                               // 8 groups per block
    int rows_per_block = (threads >> 5) * RPG;       // 64 rows
    dim3 grid((max_len + rows_per_block - 1) / rows_per_block, B, 1);
    gather_pad_fused<<<grid, threads, 0, stream>>>(
        (const f32x4*)values, y, bv, N, enc4, tgt, msk, max_len);
}

// Round 4
// 100.969 us; speedup vs baseline: 10.8798x; 10.8798x over previous
//
#include <hip/hip_runtime.h>

#ifndef B_GRAPHS
#define B_GRAPHS 512
#endif

#define ROWS_PER_GROUP 4

typedef float f32x4 __attribute__((ext_vector_type(4)));

// Kernel 1: boundary-detection offsets (bv is SORTED).
// offs[b] = lower_bound(bv, b) for b in [0, B]. For each i, all keys b in
// (bv[i-1], bv[i]] have lower_bound == i. Thread i fills that (usually empty
// or length-1) range; thread n-1 also fills the tail (bv[n-1], B].
// One coalesced pass over bv, no dependent-load chains, no atomics.
__global__ void boundary_offsets_kernel(const int* __restrict__ bv, int n,
                                        int num_graphs, int* __restrict__ offs) {
    int i = blockIdx.x * blockDim.x + threadIdx.x;
    if (i >= n) return;
    int cur  = bv[i];
    int prev = (i == 0) ? -1 : bv[i - 1];
    for (int b = prev + 1; b <= cur; ++b) offs[b] = i;
    if (i == n - 1) {
        for (int b = cur + 1; b <= num_graphs; ++b) offs[b] = n;
    }
}

// Kernel 2 (identical to measured-good R2): gather-formulated unbatch+pad.
// grid.y = graph b (offs loads wave-uniform). Each 32-lane group handles
// ROWS_PER_GROUP consecutive rows; lane moves one float4/row (D=128).
__global__ void gather_pad_kernel(const f32x4* __restrict__ vals4,
                                  const int* __restrict__ y,
                                  const int* __restrict__ offs,
                                  f32x4* __restrict__ enc4,
                                  float* __restrict__ tgt,
                                  float* __restrict__ msk,
                                  int max_len) {
    const int b     = blockIdx.y;
    const int start = offs[b];           // uniform -> s_load
    const int size  = offs[b + 1] - start;

    const int group = threadIdx.x >> 5;
    const int lane  = threadIdx.x & 31;
    const int groups_per_block = blockDim.x >> 5;
    const int pos0 = (blockIdx.x * groups_per_block + group) * ROWS_PER_GROUP;

    f32x4 v[ROWS_PER_GROUP];
    #pragma unroll
    for (int r = 0; r < ROWS_PER_GROUP; ++r) {
        int pos = pos0 + r;
        f32x4 z = {0.f, 0.f, 0.f, 0.f};
        v[r] = z;
        if (pos < size)
            v[r] = __builtin_nontemporal_load(&vals4[(size_t)(start + pos) * 32 + lane]);
    }

    const size_t rowbase = (size_t)b * max_len + pos0;
    #pragma unroll
    for (int r = 0; r < ROWS_PER_GROUP; ++r) {
        int pos = pos0 + r;
        if (pos < max_len)
            __builtin_nontemporal_store(v[r], &enc4[(rowbase + r) * 32 + lane]);
    }

    if (lane < 2) {
        #pragma unroll
        for (int r = 0; r < ROWS_PER_GROUP; ++r) {
            int pos = pos0 + r;
            if (pos < max_len) {
                bool valid = pos < size;
                if (lane == 0)
                    tgt[rowbase + r] = valid ? (float)y[start + pos] : 0.0f;
                else
                    msk[rowbase + r] = valid ? 1.0f : 0.0f;
            }
        }
    }
}

extern "C" void kernel_launch(void* const* d_in, const int* in_sizes, int n_in,
                              void* d_out, int out_size, void* d_ws, size_t ws_size,
                              hipStream_t stream) {
    const float* values = (const float*)d_in[0];
    const int*   y      = (const int*)d_in[1];
    const int*   bv     = (const int*)d_in[2];

    const int N = in_sizes[1];            // 500000 nodes
    const int D = in_sizes[0] / N;        // 128
    const int B = B_GRAPHS;               // 512 (compile-time in reference)
    const int max_len = out_size / (B * (D + 2));
    const int total_rows = B * max_len;

    int* offs = (int*)d_ws;               // B+1 ints

    {
        int threads = 256;
        int blocks = (N + threads - 1) / threads;
        boundary_offsets_kernel<<<blocks, threads, 0, stream>>>(bv, N, B, offs);
    }

    {
        f32x4* enc4 = (f32x4*)d_out;
        float* tgt  = (float*)d_out + (size_t)total_rows * D;
        float* msk  = (float*)d_out + (size_t)total_rows * (D + 1);
        int threads = 256;                                    // 8 groups/block
        int rows_per_block = (threads >> 5) * ROWS_PER_GROUP; // 32 rows
        dim3 grid((max_len + rows_per_block - 1) / rows_per_block, B, 1);
        gather_pad_kernel<<<grid, threads, 0, stream>>>(
            (const f32x4*)values, y, offs, enc4, tgt, msk, max_len);
    }
}